// Round 9
// baseline (2041.507 us; speedup 1.0000x reference)
//
#include <hip/hip_runtime.h>
#include <math.h>

#define T_DIM 8192
#define H_DIM 4096
#define I_DIM 11008

typedef int v4i  __attribute__((ext_vector_type(4)));
typedef int v16i __attribute__((ext_vector_type(16)));

#define MFMA8 __builtin_amdgcn_mfma_i32_32x32x32_i8

#define AS1(p) ((const __attribute__((address_space(1))) void*)(p))
#define AS3(p) ((__attribute__((address_space(3))) void*)(p))

// counted vmcnt wait (never 0 in steady loop) + scheduler fence
#define WAITV(N) do { asm volatile("s_waitcnt vmcnt(" #N ")" ::: "memory"); \
                      __builtin_amdgcn_sched_barrier(0); } while (0)
#define BAR() __builtin_amdgcn_s_barrier()
// counted LDS wait + scheduler fence (rule #18)
#define LGKM(N) do { asm volatile("s_waitcnt lgkmcnt(" #N ")" ::: "memory"); \
                     __builtin_amdgcn_sched_barrier(0); } while (0)

__device__ __forceinline__ v4i DSR(const char* p) {
  v4i r;
  unsigned a = (unsigned)(size_t)(const __attribute__((address_space(3))) char*)p;
  asm volatile("ds_read_b128 %0, %1" : "=v"(r) : "v"(a));
  return r;
}

// One STG = one whole 1KB fragment per wave (wave-uniform LDS base + lane*16).
#define STG(ldst, gsrc) \
  __builtin_amdgcn_global_load_lds(AS1(gsrc), AS3(ldst), 16, 0, 0)

// ---------------- pack + shuffle into MFMA-fragment order (r3/r4-verified) ----
__global__ void pack_shuf(const int* __restrict__ src, char* __restrict__ dst,
                          int nk32, long nchunk) {
  long c = (long)blockIdx.x * blockDim.x + threadIdx.x;
  long stride = (long)gridDim.x * blockDim.x;
  for (; c < nchunk; c += stride) {
    int lane = (int)(c & 63);
    long rk = c >> 6;
    long r32 = rk / nk32;
    int k32 = (int)(rk - r32 * nk32);
    const int4* s = (const int4*)(src + (r32 * 32 + (lane & 31)) * (long)(nk32 * 32)
                                      + (long)k32 * 32 + ((lane >> 5) << 4));
    int4 a = s[0], b = s[1], cc = s[2], d = s[3];
    int w0 = (a.x & 255) | ((a.y & 255) << 8) | ((a.z & 255) << 16) | (a.w << 24);
    int w1 = (b.x & 255) | ((b.y & 255) << 8) | ((b.z & 255) << 16) | (b.w << 24);
    int w2 = (cc.x & 255) | ((cc.y & 255) << 8) | ((cc.z & 255) << 16) | (cc.w << 24);
    int w3 = (d.x & 255) | ((d.y & 255) << 8) | ((d.z & 255) << 16) | (d.w << 24);
    ((int4*)dst)[c] = make_int4(w0, w1, w2, w3);
  }
}

// ---------------- gate+up fused GEMM: FAT-WAVE + counted vmcnt ----------------
// 256x128 tile, 4 waves (2M x 2N), 1 wave/SIMD, wave = 128x64 x {gate,up}.
// 16 acc tiles/wave (256 AGPR). BK=64 (2 k-steps), 3x32KB bufs, distance-2 DMA,
// counted vmcnt(8). Per step: 8 ds_read_b128 + 16 MFMA (port < MFMA pipe).
// Buf: A frag(r32idx,ks)@r32idx*2048+ks*1024 (16KB) | G @16K (8KB) | U @24K (8KB).
__global__ __launch_bounds__(256, 1) void gemm_gateup(
    const char* __restrict__ A, const char* __restrict__ Bg, const char* __restrict__ Bu,
    const float* __restrict__ ga_p, const float* __restrict__ gb,
    const float* __restrict__ ua_p, const float* __restrict__ ub,
    char* __restrict__ Q)
{
  __shared__ char lds[3][32768];
  const int tid = threadIdx.x;
  const int l = tid & 63;
  const int w = tid >> 6;          // 4 waves
  const int wm = w >> 1, wn = w & 1;
  const int li32 = l & 31, kg2 = l >> 5;

  // XCD-chunked bijection (nwg=2752, %8==0) + 4x2 supertile.
  const int q8 = 2752 / 8;
  int bid = blockIdx.x;
  int wgid = (bid & 7) * q8 + (bid >> 3);
  int st = wgid >> 3, r = wgid & 7;
  int sm = st / 43, sn = st - sm * 43;
  const int m0 = (sm * 4 + (r & 3)) * 256;
  const int n0 = (sn * 2 + (r >> 2)) * 128;

  const int NK = H_DIM / 32;   // 128 k32 blocks
  const int NT = H_DIM / 64;   // 64 K-tiles (BK=64)

  v16i accg[4][2], accu[4][2];
#pragma unroll
  for (int i = 0; i < 4; ++i)
#pragma unroll
    for (int n = 0; n < 2; ++n)
#pragma unroll
      for (int j = 0; j < 16; ++j) { accg[i][n][j] = 0; accu[i][n][j] = 0; }

  const int lo = l * 16;
  // Staging: wave w stages A r32idx {2w,2w+1} x ks{0,1} + G,U n32idx=w x ks{0,1}
  // = 8 DMAs/tile.
  const char* pA0 = A  + ((size_t)((m0 >> 5) + 2 * w)     * NK) * 1024 + lo;
  const char* pA1 = A  + ((size_t)((m0 >> 5) + 2 * w + 1) * NK) * 1024 + lo;
  const char* pG  = Bg + ((size_t)((n0 >> 5) + w) * NK) * 1024 + lo;
  const char* pU  = Bu + ((size_t)((n0 >> 5) + w) * NK) * 1024 + lo;
  const int dA = w * 4096 + lo;
  const int dG = 16384 + w * 2048 + lo;
  const int dU = 24576 + w * 2048 + lo;

#define STAGE_GU(SB, tt)                                                  \
  do {                                                                    \
    size_t so = (size_t)(tt) * 2048;                                      \
    STG((SB) + dA,        pA0 + so);                                      \
    STG((SB) + dA + 1024, pA0 + so + 1024);                               \
    STG((SB) + dA + 2048, pA1 + so);                                      \
    STG((SB) + dA + 3072, pA1 + so + 1024);                               \
    STG((SB) + dG,        pG + so);                                       \
    STG((SB) + dG + 1024, pG + so + 1024);                                \
    STG((SB) + dU,        pU + so);                                       \
    STG((SB) + dU + 1024, pU + so + 1024);                                \
  } while (0)

  const int oA0 = (wm * 4 + 0) * 2048 + lo;
  const int oA1 = (wm * 4 + 1) * 2048 + lo;
  const int oA2 = (wm * 4 + 2) * 2048 + lo;
  const int oA3 = (wm * 4 + 3) * 2048 + lo;
  const int oG0 = 16384 + (wn * 2 + 0) * 2048 + lo;
  const int oG1 = 16384 + (wn * 2 + 1) * 2048 + lo;
  const int oU0 = 24576 + (wn * 2 + 0) * 2048 + lo;
  const int oU1 = 24576 + (wn * 2 + 1) * 2048 + lo;

  v4i E0, E1, E2, E3, Eg0, Eg1, Eu0, Eu1;
  v4i O0, O1, O2, O3, Og0, Og1, Ou0, Ou1;

#define RD_GU(S, B, s)                                                    \
  do {                                                                    \
    S##0 = DSR((B) + oA0 + (s) * 1024);                                   \
    S##1 = DSR((B) + oA1 + (s) * 1024);                                   \
    S##2 = DSR((B) + oA2 + (s) * 1024);                                   \
    S##3 = DSR((B) + oA3 + (s) * 1024);                                   \
    S##g0 = DSR((B) + oG0 + (s) * 1024);                                  \
    S##g1 = DSR((B) + oG1 + (s) * 1024);                                  \
    S##u0 = DSR((B) + oU0 + (s) * 1024);                                  \
    S##u1 = DSR((B) + oU1 + (s) * 1024);                                  \
  } while (0)

#define MM_GU(S)                                                          \
  do {                                                                    \
    __builtin_amdgcn_s_setprio(1);                                        \
    accg[0][0] = MFMA8(S##0, S##g0, accg[0][0], 0, 0, 0);                 \
    accg[0][1] = MFMA8(S##0, S##g1, accg[0][1], 0, 0, 0);                 \
    accu[0][0] = MFMA8(S##0, S##u0, accu[0][0], 0, 0, 0);                 \
    accu[0][1] = MFMA8(S##0, S##u1, accu[0][1], 0, 0, 0);                 \
    accg[1][0] = MFMA8(S##1, S##g0, accg[1][0], 0, 0, 0);                 \
    accg[1][1] = MFMA8(S##1, S##g1, accg[1][1], 0, 0, 0);                 \
    accu[1][0] = MFMA8(S##1, S##u0, accu[1][0], 0, 0, 0);                 \
    accu[1][1] = MFMA8(S##1, S##u1, accu[1][1], 0, 0, 0);                 \
    accg[2][0] = MFMA8(S##2, S##g0, accg[2][0], 0, 0, 0);                 \
    accg[2][1] = MFMA8(S##2, S##g1, accg[2][1], 0, 0, 0);                 \
    accu[2][0] = MFMA8(S##2, S##u0, accu[2][0], 0, 0, 0);                 \
    accu[2][1] = MFMA8(S##2, S##u1, accu[2][1], 0, 0, 0);                 \
    accg[3][0] = MFMA8(S##3, S##g0, accg[3][0], 0, 0, 0);                 \
    accg[3][1] = MFMA8(S##3, S##g1, accg[3][1], 0, 0, 0);                 \
    accu[3][0] = MFMA8(S##3, S##u0, accu[3][0], 0, 0, 0);                 \
    accu[3][1] = MFMA8(S##3, S##u1, accu[3][1], 0, 0, 0);                 \
    __builtin_amdgcn_s_setprio(0);                                        \
  } while (0)

  char* b0 = lds[0];
  char* b1 = lds[1];
  char* b2 = lds[2];

  {  // Prologue: stage tiles 0,1; certify tile 0 via counted vmcnt(8).
    STAGE_GU(b0, 0);
    STAGE_GU(b1, 1);
    WAITV(8);
    BAR();
    RD_GU(E, b0, 0);
  }

  for (int t = 0; t < NT; ++t) {
    const int ts = (t + 2 < NT) ? (t + 2) : (NT - 1);  // tail-clamped dup
    // P0: read s1; stage tile t+2 (8 DMAs); MFMA(s0)
    RD_GU(O, b0, 1);
    STAGE_GU(b2, ts);
    LGKM(8);          // retire E reads (issue order: E then O)
    MM_GU(E);
    // P1: certify buf(t+1) (its 8 DMAs issued last iter); close O reads
    // (formal rotation hazard); barrier; read next tile's s0; MFMA(s1)
    WAITV(8);
    LGKM(0);
    BAR();
    RD_GU(E, b1, 0);
    MM_GU(O);
    char* tmp = b0; b0 = b1; b1 = b2; b2 = tmp;
  }
  WAITV(0);   // drain tail DMAs
#undef RD_GU
#undef MM_GU
#undef STAGE_GU

  // Epilogue (r5-verified fat-wave maps): dequant -> SiLU(g)*u -> rint ->
  // clamp -> int8, written in DOWN's shuffled layout [r32][k32][lane][16B].
  const float ga = *ga_p, ua = *ua_p;
  const int lanehi = ((li32 >> 4) & 1) << 5;
  const int bytelo = li32 & 15;
  const int NKQ = I_DIM / 32;  // 344
#pragma unroll
  for (int ni = 0; ni < 2; ++ni) {
    const int col = n0 + wn * 64 + ni * 32 + li32;
    const float gbv = gb[col], ubv = ub[col];
    const int k32q = (n0 >> 5) + wn * 2 + ni;
#pragma unroll
    for (int mi = 0; mi < 4; ++mi) {
      const int r32q = (m0 >> 5) + wm * 4 + mi;
      char* qbase = Q + ((size_t)(r32q * NKQ + k32q) << 10);
#pragma unroll
      for (int rq = 0; rq < 4; ++rq) {
#pragma unroll
        for (int rr = 0; rr < 4; ++rr) {
          const int rg = rq * 4 + rr;
          const int rowin = kg2 * 4 + rq * 8 + rr;
          float g = (float)accg[mi][ni][rg] * ga + gbv;
          float u = (float)accu[mi][ni][rg] * ua + ubv;
          float x1 = g / (1.0f + expf(-g));
          float x = rintf(x1 * u);
          x = fminf(fmaxf(x, -128.0f), 127.0f);
          qbase[((rowin | lanehi) << 4) + bytelo] = (char)(int)x;
        }
      }
    }
  }
}

// ---------------- down GEMM: FAT-WAVE + counted vmcnt ----------------
// 256x256 tile, 4 waves (2M x 2N), 1 wave/SIMD, wave = 128x128, acc[4][4]
// (256 AGPR). BK=64, 3x32KB bufs, distance-2, counted vmcnt(8).
// Buf: A @0 (16KB, frag(r32idx,ks)@r32idx*2048+ks*1024) | B @16K (16KB).
__global__ __launch_bounds__(256, 1) void gemm_down(
    const char* __restrict__ Qm, const char* __restrict__ Bd,
    const float* __restrict__ da_p, const float* __restrict__ db,
    float* __restrict__ out)
{
  __shared__ char lds[3][32768];
  const int tid = threadIdx.x;
  const int l = tid & 63;
  const int w = tid >> 6;
  const int wm = w >> 1, wn = w & 1;
  const int li32 = l & 31, kg2 = l >> 5;

  const int q8 = 512 / 8;
  int bid = blockIdx.x;
  int wgid = (bid & 7) * q8 + (bid >> 3);
  int st = wgid >> 3, r = wgid & 7;
  int sm = st >> 3, sn = st & 7;
  const int m0 = (sm * 4 + (r & 3)) * 256;
  const int n0 = (sn * 2 + (r >> 2)) * 256;

  const int NK = I_DIM / 32;   // 344
  const int NT = I_DIM / 64;   // 172 K-tiles

  v16i acc[4][4];
#pragma unroll
  for (int i = 0; i < 4; ++i)
#pragma unroll
    for (int n = 0; n < 4; ++n)
#pragma unroll
      for (int j = 0; j < 16; ++j) acc[i][n][j] = 0;

  const int lo = l * 16;
  const char* pA0 = Qm + ((size_t)((m0 >> 5) + 2 * w)     * NK) * 1024 + lo;
  const char* pA1 = Qm + ((size_t)((m0 >> 5) + 2 * w + 1) * NK) * 1024 + lo;
  const char* pB0 = Bd + ((size_t)((n0 >> 5) + 2 * w)     * NK) * 1024 + lo;
  const char* pB1 = Bd + ((size_t)((n0 >> 5) + 2 * w + 1) * NK) * 1024 + lo;
  const int dA = w * 4096 + lo;
  const int dB = 16384 + w * 4096 + lo;

#define STAGE_DN(SB, tt)                                                  \
  do {                                                                    \
    size_t so = (size_t)(tt) * 2048;                                      \
    STG((SB) + dA,        pA0 + so);                                      \
    STG((SB) + dA + 1024, pA0 + so + 1024);                               \
    STG((SB) + dA + 2048, pA1 + so);                                      \
    STG((SB) + dA + 3072, pA1 + so + 1024);                               \
    STG((SB) + dB,        pB0 + so);                                      \
    STG((SB) + dB + 1024, pB0 + so + 1024);                               \
    STG((SB) + dB + 2048, pB1 + so);                                      \
    STG((SB) + dB + 3072, pB1 + so + 1024);                               \
  } while (0)

  const int oA0 = (wm * 4 + 0) * 2048 + lo;
  const int oA1 = (wm * 4 + 1) * 2048 + lo;
  const int oA2 = (wm * 4 + 2) * 2048 + lo;
  const int oA3 = (wm * 4 + 3) * 2048 + lo;
  const int oB0 = 16384 + (wn * 4 + 0) * 2048 + lo;
  const int oB1 = 16384 + (wn * 4 + 1) * 2048 + lo;
  const int oB2 = 16384 + (wn * 4 + 2) * 2048 + lo;
  const int oB3 = 16384 + (wn * 4 + 3) * 2048 + lo;

  v4i E0, E1, E2, E3, Eb0, Eb1, Eb2, Eb3;
  v4i O0, O1, O2, O3, Ob0, Ob1, Ob2, Ob3;

#define RD_DN(S, B, s)                                                    \
  do {                                                                    \
    S##0 = DSR((B) + oA0 + (s) * 1024);                                   \
    S##1 = DSR((B) + oA1 + (s) * 1024);                                   \
    S##2 = DSR((B) + oA2 + (s) * 1024);                                   \
    S##3 = DSR((B) + oA3 + (s) * 1024);                                   \
    S##b0 = DSR((B) + oB0 + (s) * 1024);                                  \
    S##b1 = DSR((B) + oB1 + (s) * 1024);                                  \
    S##b2 = DSR((B) + oB2 + (s) * 1024);                                  \
    S##b3 = DSR((B) + oB3 + (s) * 1024);                                  \
  } while (0)

#define MM_DN(S)                                                          \
  do {                                                                    \
    __builtin_amdgcn_s_setprio(1);                                        \
    acc[0][0] = MFMA8(S##0, S##b0, acc[0][0], 0, 0, 0);                   \
    acc[0][1] = MFMA8(S##0, S##b1, acc[0][1], 0, 0, 0);                   \
    acc[0][2] = MFMA8(S##0, S##b2, acc[0][2], 0, 0, 0);                   \
    acc[0][3] = MFMA8(S##0, S##b3, acc[0][3], 0, 0, 0);                   \
    acc[1][0] = MFMA8(S##1, S##b0, acc[1][0], 0, 0, 0);                   \
    acc[1][1] = MFMA8(S##1, S##b1, acc[1][1], 0, 0, 0);                   \
    acc[1][2] = MFMA8(S##1, S##b2, acc[1][2], 0, 0, 0);                   \
    acc[1][3] = MFMA8(S##1, S##b3, acc[1][3], 0, 0, 0);                   \
    acc[2][0] = MFMA8(S##2, S##b0, acc[2][0], 0, 0, 0);                   \
    acc[2][1] = MFMA8(S##2, S##b1, acc[2][1], 0, 0, 0);                   \
    acc[2][2] = MFMA8(S##2, S##b2, acc[2][2], 0, 0, 0);                   \
    acc[2][3] = MFMA8(S##2, S##b3, acc[2][3], 0, 0, 0);                   \
    acc[3][0] = MFMA8(S##3, S##b0, acc[3][0], 0, 0, 0);                   \
    acc[3][1] = MFMA8(S##3, S##b1, acc[3][1], 0, 0, 0);                   \
    acc[3][2] = MFMA8(S##3, S##b2, acc[3][2], 0, 0, 0);                   \
    acc[3][3] = MFMA8(S##3, S##b3, acc[3][3], 0, 0, 0);                   \
    __builtin_amdgcn_s_setprio(0);                                        \
  } while (0)

  char* b0 = lds[0];
  char* b1 = lds[1];
  char* b2 = lds[2];

  {
    STAGE_DN(b0, 0);
    STAGE_DN(b1, 1);
    WAITV(8);
    BAR();
    RD_DN(E, b0, 0);
  }

  for (int t = 0; t < NT; ++t) {
    const int ts = (t + 2 < NT) ? (t + 2) : (NT - 1);
    RD_DN(O, b0, 1);
    STAGE_DN(b2, ts);
    LGKM(8);
    MM_DN(E);

    WAITV(8);
    LGKM(0);
    BAR();
    RD_DN(E, b1, 0);
    MM_DN(O);
    char* tmp = b0; b0 = b1; b1 = b2; b2 = tmp;
  }
  WAITV(0);
#undef RD_DN
#undef MM_DN
#undef STAGE_DN

  const float da = *da_p;
#pragma unroll
  for (int ni = 0; ni < 4; ++ni) {
    const int col = n0 + wn * 128 + ni * 32 + li32;
    const float dbv = db[col];
#pragma unroll
    for (int mi = 0; mi < 4; ++mi) {
      const int rowb = m0 + wm * 128 + mi * 32 + kg2 * 4;
#pragma unroll
      for (int rq = 0; rq < 4; ++rq) {
#pragma unroll
        for (int rr = 0; rr < 4; ++rr)
          out[(size_t)(rowb + rq * 8 + rr) * H_DIM + col] =
              (float)acc[mi][ni][rq * 4 + rr] * da + dbv;
      }
    }
  }
}

extern "C" void kernel_launch(void* const* d_in, const int* in_sizes, int n_in,
                              void* d_out, int out_size, void* d_ws, size_t ws_size,
                              hipStream_t stream) {
  const int*   hs = (const int*)d_in[0];
  const int*   gw = (const int*)d_in[1];
  const float* ga = (const float*)d_in[2];
  const float* gb = (const float*)d_in[3];
  const int*   uw = (const int*)d_in[4];
  const float* ua = (const float*)d_in[5];
  const float* ub = (const float*)d_in[6];
  const int*   dw = (const int*)d_in[7];
  const float* da = (const float*)d_in[8];
  const float* db = (const float*)d_in[9];

  char* ws   = (char*)d_ws;
  char* hidS = ws;                                  // [256][128][64][16] shuffled
  char* gS   = hidS + (size_t)T_DIM * H_DIM;        // [344][128][64][16]
  char* uS   = gS   + (size_t)I_DIM * H_DIM;
  char* dS   = uS   + (size_t)I_DIM * H_DIM;        // [128][344][64][16]
  char* qS   = dS   + (size_t)H_DIM * I_DIM;        // [256][344][64][16]

  pack_shuf<<<2048, 256, 0, stream>>>(hs, hidS, H_DIM / 32, (long)T_DIM * H_DIM / 16);
  pack_shuf<<<2048, 256, 0, stream>>>(gw, gS,   H_DIM / 32, (long)I_DIM * H_DIM / 16);
  pack_shuf<<<2048, 256, 0, stream>>>(uw, uS,   H_DIM / 32, (long)I_DIM * H_DIM / 16);
  pack_shuf<<<2048, 256, 0, stream>>>(dw, dS,   I_DIM / 32, (long)H_DIM * I_DIM / 16);

  gemm_gateup<<<2752, 256, 0, stream>>>(hidS, gS, uS, ga, gb, ua, ub, qS);
  gemm_down<<<512, 256, 0, stream>>>(qS, dS, da, db, (float*)d_out);
}

// Round 10
// 2018.399 us; speedup vs baseline: 1.0114x; 1.0114x over previous
//
#include <hip/hip_runtime.h>
#include <math.h>

#define T_DIM 8192
#define H_DIM 4096
#define I_DIM 11008

typedef int v4i  __attribute__((ext_vector_type(4)));
typedef int v16i __attribute__((ext_vector_type(16)));

#define MFMA8 __builtin_amdgcn_mfma_i32_32x32x32_i8

#define AS1(p) ((const __attribute__((address_space(1))) void*)(p))
#define AS3(p) ((__attribute__((address_space(3))) void*)(p))

// plain counted vmcnt wait (no sched fence: no MFMA hazard at these points)
#define WAITV(N) asm volatile("s_waitcnt vmcnt(" #N ")" ::: "memory")
#define BAR() __builtin_amdgcn_s_barrier()
// counted LDS wait + scheduler fence (rule #18: closes ds_read -> MFMA)
#define LGKM(N) do { asm volatile("s_waitcnt lgkmcnt(" #N ")" ::: "memory"); \
                     __builtin_amdgcn_sched_barrier(0); } while (0)

__device__ __forceinline__ v4i DSR(const char* p) {
  v4i r;
  unsigned a = (unsigned)(size_t)(const __attribute__((address_space(3))) char*)p;
  asm volatile("ds_read_b128 %0, %1" : "=v"(r) : "v"(a));
  return r;
}

// One STG = one whole 1KB fragment per wave (wave-uniform LDS base + lane*16).
#define STG(ldst, gsrc) \
  __builtin_amdgcn_global_load_lds(AS1(gsrc), AS3(ldst), 16, 0, 0)

// ---------------- pack + shuffle into MFMA-fragment order (r3/r4-verified) ----
__global__ void pack_shuf(const int* __restrict__ src, char* __restrict__ dst,
                          int nk32, long nchunk) {
  long c = (long)blockIdx.x * blockDim.x + threadIdx.x;
  long stride = (long)gridDim.x * blockDim.x;
  for (; c < nchunk; c += stride) {
    int lane = (int)(c & 63);
    long rk = c >> 6;
    long r32 = rk / nk32;
    int k32 = (int)(rk - r32 * nk32);
    const int4* s = (const int4*)(src + (r32 * 32 + (lane & 31)) * (long)(nk32 * 32)
                                      + (long)k32 * 32 + ((lane >> 5) << 4));
    int4 a = s[0], b = s[1], cc = s[2], d = s[3];
    int w0 = (a.x & 255) | ((a.y & 255) << 8) | ((a.z & 255) << 16) | (a.w << 24);
    int w1 = (b.x & 255) | ((b.y & 255) << 8) | ((b.z & 255) << 16) | (b.w << 24);
    int w2 = (cc.x & 255) | ((cc.y & 255) << 8) | ((cc.z & 255) << 16) | (cc.w << 24);
    int w3 = (d.x & 255) | ((d.y & 255) << 8) | ((d.z & 255) << 16) | (d.w << 24);
    ((int4*)dst)[c] = make_int4(w0, w1, w2, w3);
  }
}

// ---------------- gate+up fused GEMM: FAT-WAVE, minimal fencing ----------------
// 256x128 tile, 4 waves (2M x 2N), 1 wave/SIMD, wave = 128x64 x {gate,up}.
// 16 acc tiles/wave. BK=64, 3x32KB bufs, distance-2 DMA, counted vmcnt(8).
// Per step: 8 ds_read_b128 + 16 MFMA. Exactly 2 sched fences per tile (rule-18).
__global__ __launch_bounds__(256, 1) void gemm_gateup(
    const char* __restrict__ A, const char* __restrict__ Bg, const char* __restrict__ Bu,
    const float* __restrict__ ga_p, const float* __restrict__ gb,
    const float* __restrict__ ua_p, const float* __restrict__ ub,
    char* __restrict__ Q)
{
  __shared__ char lds[98304];
  const int tid = threadIdx.x;
  const int l = tid & 63;
  const int w = tid >> 6;          // 4 waves
  const int wm = w >> 1, wn = w & 1;
  const int li32 = l & 31, kg2 = l >> 5;

  // XCD-chunked bijection (nwg=2752, %8==0) + 4x2 supertile.
  const int q8 = 2752 / 8;
  int bid = blockIdx.x;
  int wgid = (bid & 7) * q8 + (bid >> 3);
  int st = wgid >> 3, r = wgid & 7;
  int sm = st / 43, sn = st - sm * 43;
  const int m0 = (sm * 4 + (r & 3)) * 256;
  const int n0 = (sn * 2 + (r >> 2)) * 128;

  const int NK = H_DIM / 32;   // 128
  const int NT = H_DIM / 64;   // 64 K-tiles

  v16i accg[4][2], accu[4][2];
#pragma unroll
  for (int i = 0; i < 4; ++i)
#pragma unroll
    for (int n = 0; n < 2; ++n)
#pragma unroll
      for (int j = 0; j < 16; ++j) { accg[i][n][j] = 0; accu[i][n][j] = 0; }

  const int lo = l * 16;
  // Staging: wave w stages A r32idx {2w,2w+1} x ks{0,1} + G,U n32idx=w x ks{0,1}.
  const char* pA0 = A  + ((size_t)((m0 >> 5) + 2 * w)     * NK) * 1024 + lo;
  const char* pA1 = A  + ((size_t)((m0 >> 5) + 2 * w + 1) * NK) * 1024 + lo;
  const char* pG  = Bg + ((size_t)((n0 >> 5) + w) * NK) * 1024 + lo;
  const char* pU  = Bu + ((size_t)((n0 >> 5) + w) * NK) * 1024 + lo;
  const int dA = w * 4096 + lo;
  const int dG = 16384 + w * 2048 + lo;
  const int dU = 24576 + w * 2048 + lo;

#define STAGE_GU(bo, tt)                                                  \
  do {                                                                    \
    size_t so = (size_t)(tt) * 2048;                                      \
    STG(lds + (bo) + dA,        pA0 + so);                                \
    STG(lds + (bo) + dA + 1024, pA0 + so + 1024);                         \
    STG(lds + (bo) + dA + 2048, pA1 + so);                                \
    STG(lds + (bo) + dA + 3072, pA1 + so + 1024);                         \
    STG(lds + (bo) + dG,        pG + so);                                 \
    STG(lds + (bo) + dG + 1024, pG + so + 1024);                          \
    STG(lds + (bo) + dU,        pU + so);                                 \
    STG(lds + (bo) + dU + 1024, pU + so + 1024);                          \
  } while (0)

  const int oA0 = (wm * 4 + 0) * 2048 + lo;
  const int oA1 = (wm * 4 + 1) * 2048 + lo;
  const int oA2 = (wm * 4 + 2) * 2048 + lo;
  const int oA3 = (wm * 4 + 3) * 2048 + lo;
  const int oG0 = 16384 + (wn * 2 + 0) * 2048 + lo;
  const int oG1 = 16384 + (wn * 2 + 1) * 2048 + lo;
  const int oU0 = 24576 + (wn * 2 + 0) * 2048 + lo;
  const int oU1 = 24576 + (wn * 2 + 1) * 2048 + lo;

  v4i E0, E1, E2, E3, Eg0, Eg1, Eu0, Eu1;
  v4i O0, O1, O2, O3, Og0, Og1, Ou0, Ou1;

#define RD_GU(S, bo, s)                                                   \
  do {                                                                    \
    S##0 = DSR(lds + (bo) + oA0 + (s) * 1024);                            \
    S##1 = DSR(lds + (bo) + oA1 + (s) * 1024);                            \
    S##2 = DSR(lds + (bo) + oA2 + (s) * 1024);                            \
    S##3 = DSR(lds + (bo) + oA3 + (s) * 1024);                            \
    S##g0 = DSR(lds + (bo) + oG0 + (s) * 1024);                           \
    S##g1 = DSR(lds + (bo) + oG1 + (s) * 1024);                           \
    S##u0 = DSR(lds + (bo) + oU0 + (s) * 1024);                           \
    S##u1 = DSR(lds + (bo) + oU1 + (s) * 1024);                           \
  } while (0)

#define MM_GU(S)                                                          \
  do {                                                                    \
    __builtin_amdgcn_s_setprio(1);                                        \
    accg[0][0] = MFMA8(S##0, S##g0, accg[0][0], 0, 0, 0);                 \
    accg[0][1] = MFMA8(S##0, S##g1, accg[0][1], 0, 0, 0);                 \
    accu[0][0] = MFMA8(S##0, S##u0, accu[0][0], 0, 0, 0);                 \
    accu[0][1] = MFMA8(S##0, S##u1, accu[0][1], 0, 0, 0);                 \
    accg[1][0] = MFMA8(S##1, S##g0, accg[1][0], 0, 0, 0);                 \
    accg[1][1] = MFMA8(S##1, S##g1, accg[1][1], 0, 0, 0);                 \
    accu[1][0] = MFMA8(S##1, S##u0, accu[1][0], 0, 0, 0);                 \
    accu[1][1] = MFMA8(S##1, S##u1, accu[1][1], 0, 0, 0);                 \
    accg[2][0] = MFMA8(S##2, S##g0, accg[2][0], 0, 0, 0);                 \
    accg[2][1] = MFMA8(S##2, S##g1, accg[2][1], 0, 0, 0);                 \
    accu[2][0] = MFMA8(S##2, S##u0, accu[2][0], 0, 0, 0);                 \
    accu[2][1] = MFMA8(S##2, S##u1, accu[2][1], 0, 0, 0);                 \
    accg[3][0] = MFMA8(S##3, S##g0, accg[3][0], 0, 0, 0);                 \
    accg[3][1] = MFMA8(S##3, S##g1, accg[3][1], 0, 0, 0);                 \
    accu[3][0] = MFMA8(S##3, S##u0, accu[3][0], 0, 0, 0);                 \
    accu[3][1] = MFMA8(S##3, S##u1, accu[3][1], 0, 0, 0);                 \
    __builtin_amdgcn_s_setprio(0);                                        \
  } while (0)

  int bo0 = 0, bo1 = 32768, bo2 = 65536;

  {  // Prologue: stage tiles 0,1; certify tile 0 via counted vmcnt(8).
    STAGE_GU(bo0, 0);
    STAGE_GU(bo1, 1);
    WAITV(8);
    BAR();
    RD_GU(E, bo0, 0);
  }

  for (int t = 0; t < NT; ++t) {
    const int ts = (t + 2 < NT) ? (t + 2) : (NT - 1);  // tail-clamped dup
    // P0: read s1; stage tile t+2; MFMA(s0)
    RD_GU(O, bo0, 1);
    STAGE_GU(bo2, ts);
    LGKM(8);          // close E reads (retire 8 oldest of 16)
    MM_GU(E);
    // P1: certify buf(t+1) (counted: its 8 DMAs issued a full tile ago);
    // close ALL reads of bo0 before anyone stages into it next tile; sync;
    // read next tile's s0 (completes under MM(O)); MFMA(s1).
    WAITV(8);
    LGKM(0);
    BAR();
    RD_GU(E, bo1, 0);
    MM_GU(O);
    int tmp = bo0; bo0 = bo1; bo1 = bo2; bo2 = tmp;
  }
  WAITV(0);   // drain tail DMAs
  asm volatile("s_waitcnt lgkmcnt(0)" ::: "memory");
#undef RD_GU
#undef MM_GU
#undef STAGE_GU

  // Epilogue (r5-verified fat-wave maps): dequant -> SiLU(g)*u -> rint ->
  // clamp -> int8, written in DOWN's shuffled layout [r32][k32][lane][16B].
  const float ga = *ga_p, ua = *ua_p;
  const int lanehi = ((li32 >> 4) & 1) << 5;
  const int bytelo = li32 & 15;
  const int NKQ = I_DIM / 32;  // 344
#pragma unroll
  for (int ni = 0; ni < 2; ++ni) {
    const int col = n0 + wn * 64 + ni * 32 + li32;
    const float gbv = gb[col], ubv = ub[col];
    const int k32q = (n0 >> 5) + wn * 2 + ni;
#pragma unroll
    for (int mi = 0; mi < 4; ++mi) {
      const int r32q = (m0 >> 5) + wm * 4 + mi;
      char* qbase = Q + ((size_t)(r32q * NKQ + k32q) << 10);
#pragma unroll
      for (int rq = 0; rq < 4; ++rq) {
#pragma unroll
        for (int rr = 0; rr < 4; ++rr) {
          const int rg = rq * 4 + rr;
          const int rowin = kg2 * 4 + rq * 8 + rr;
          float g = (float)accg[mi][ni][rg] * ga + gbv;
          float u = (float)accu[mi][ni][rg] * ua + ubv;
          float x1 = g / (1.0f + expf(-g));
          float x = rintf(x1 * u);
          x = fminf(fmaxf(x, -128.0f), 127.0f);
          qbase[((rowin | lanehi) << 4) + bytelo] = (char)(int)x;
        }
      }
    }
  }
}

// ---------------- down GEMM: FAT-WAVE, minimal fencing ----------------
// 256x256 tile, 4 waves (2M x 2N), 1 wave/SIMD, wave = 128x128, acc[4][4].
// BK=64, 3x32KB bufs, distance-2, counted vmcnt(8). A @0 (16KB) | B @16K (16KB).
__global__ __launch_bounds__(256, 1) void gemm_down(
    const char* __restrict__ Qm, const char* __restrict__ Bd,
    const float* __restrict__ da_p, const float* __restrict__ db,
    float* __restrict__ out)
{
  __shared__ char lds[98304];
  const int tid = threadIdx.x;
  const int l = tid & 63;
  const int w = tid >> 6;
  const int wm = w >> 1, wn = w & 1;
  const int li32 = l & 31, kg2 = l >> 5;

  const int q8 = 512 / 8;
  int bid = blockIdx.x;
  int wgid = (bid & 7) * q8 + (bid >> 3);
  int st = wgid >> 3, r = wgid & 7;
  int sm = st >> 3, sn = st & 7;
  const int m0 = (sm * 4 + (r & 3)) * 256;
  const int n0 = (sn * 2 + (r >> 2)) * 256;

  const int NK = I_DIM / 32;   // 344
  const int NT = I_DIM / 64;   // 172 K-tiles

  v16i acc[4][4];
#pragma unroll
  for (int i = 0; i < 4; ++i)
#pragma unroll
    for (int n = 0; n < 4; ++n)
#pragma unroll
      for (int j = 0; j < 16; ++j) acc[i][n][j] = 0;

  const int lo = l * 16;
  const char* pA0 = Qm + ((size_t)((m0 >> 5) + 2 * w)     * NK) * 1024 + lo;
  const char* pA1 = Qm + ((size_t)((m0 >> 5) + 2 * w + 1) * NK) * 1024 + lo;
  const char* pB0 = Bd + ((size_t)((n0 >> 5) + 2 * w)     * NK) * 1024 + lo;
  const char* pB1 = Bd + ((size_t)((n0 >> 5) + 2 * w + 1) * NK) * 1024 + lo;
  const int dA = w * 4096 + lo;
  const int dB = 16384 + w * 4096 + lo;

#define STAGE_DN(bo, tt)                                                  \
  do {                                                                    \
    size_t so = (size_t)(tt) * 2048;                                      \
    STG(lds + (bo) + dA,        pA0 + so);                                \
    STG(lds + (bo) + dA + 1024, pA0 + so + 1024);                         \
    STG(lds + (bo) + dA + 2048, pA1 + so);                                \
    STG(lds + (bo) + dA + 3072, pA1 + so + 1024);                         \
    STG(lds + (bo) + dB,        pB0 + so);                                \
    STG(lds + (bo) + dB + 1024, pB0 + so + 1024);                         \
    STG(lds + (bo) + dB + 2048, pB1 + so);                                \
    STG(lds + (bo) + dB + 3072, pB1 + so + 1024);                         \
  } while (0)

  const int oA0 = (wm * 4 + 0) * 2048 + lo;
  const int oA1 = (wm * 4 + 1) * 2048 + lo;
  const int oA2 = (wm * 4 + 2) * 2048 + lo;
  const int oA3 = (wm * 4 + 3) * 2048 + lo;
  const int oB0 = 16384 + (wn * 4 + 0) * 2048 + lo;
  const int oB1 = 16384 + (wn * 4 + 1) * 2048 + lo;
  const int oB2 = 16384 + (wn * 4 + 2) * 2048 + lo;
  const int oB3 = 16384 + (wn * 4 + 3) * 2048 + lo;

  v4i E0, E1, E2, E3, Eb0, Eb1, Eb2, Eb3;
  v4i O0, O1, O2, O3, Ob0, Ob1, Ob2, Ob3;

#define RD_DN(S, bo, s)                                                   \
  do {                                                                    \
    S##0 = DSR(lds + (bo) + oA0 + (s) * 1024);                            \
    S##1 = DSR(lds + (bo) + oA1 + (s) * 1024);                            \
    S##2 = DSR(lds + (bo) + oA2 + (s) * 1024);                            \
    S##3 = DSR(lds + (bo) + oA3 + (s) * 1024);                            \
    S##b0 = DSR(lds + (bo) + oB0 + (s) * 1024);                           \
    S##b1 = DSR(lds + (bo) + oB1 + (s) * 1024);                           \
    S##b2 = DSR(lds + (bo) + oB2 + (s) * 1024);                           \
    S##b3 = DSR(lds + (bo) + oB3 + (s) * 1024);                           \
  } while (0)

#define MM_DN(S)                                                          \
  do {                                                                    \
    __builtin_amdgcn_s_setprio(1);                                        \
    acc[0][0] = MFMA8(S##0, S##b0, acc[0][0], 0, 0, 0);                   \
    acc[0][1] = MFMA8(S##0, S##b1, acc[0][1], 0, 0, 0);                   \
    acc[0][2] = MFMA8(S##0, S##b2, acc[0][2], 0, 0, 0);                   \
    acc[0][3] = MFMA8(S##0, S##b3, acc[0][3], 0, 0, 0);                   \
    acc[1][0] = MFMA8(S##1, S##b0, acc[1][0], 0, 0, 0);                   \
    acc[1][1] = MFMA8(S##1, S##b1, acc[1][1], 0, 0, 0);                   \
    acc[1][2] = MFMA8(S##1, S##b2, acc[1][2], 0, 0, 0);                   \
    acc[1][3] = MFMA8(S##1, S##b3, acc[1][3], 0, 0, 0);                   \
    acc[2][0] = MFMA8(S##2, S##b0, acc[2][0], 0, 0, 0);                   \
    acc[2][1] = MFMA8(S##2, S##b1, acc[2][1], 0, 0, 0);                   \
    acc[2][2] = MFMA8(S##2, S##b2, acc[2][2], 0, 0, 0);                   \
    acc[2][3] = MFMA8(S##2, S##b3, acc[2][3], 0, 0, 0);                   \
    acc[3][0] = MFMA8(S##3, S##b0, acc[3][0], 0, 0, 0);                   \
    acc[3][1] = MFMA8(S##3, S##b1, acc[3][1], 0, 0, 0);                   \
    acc[3][2] = MFMA8(S##3, S##b2, acc[3][2], 0, 0, 0);                   \
    acc[3][3] = MFMA8(S##3, S##b3, acc[3][3], 0, 0, 0);                   \
    __builtin_amdgcn_s_setprio(0);                                        \
  } while (0)

  int bo0 = 0, bo1 = 32768, bo2 = 65536;

  {
    STAGE_DN(bo0, 0);
    STAGE_DN(bo1, 1);
    WAITV(8);
    BAR();
    RD_DN(E, bo0, 0);
  }

  for (int t = 0; t < NT; ++t) {
    const int ts = (t + 2 < NT) ? (t + 2) : (NT - 1);
    RD_DN(O, bo0, 1);
    STAGE_DN(bo2, ts);
    LGKM(8);
    MM_DN(E);

    WAITV(8);
    LGKM(0);
    BAR();
    RD_DN(E, bo1, 0);
    MM_DN(O);
    int tmp = bo0; bo0 = bo1; bo1 = bo2; bo2 = tmp;
  }
  WAITV(0);
  asm volatile("s_waitcnt lgkmcnt(0)" ::: "memory");
#undef RD_DN
#undef MM_DN
#undef STAGE_DN

  const float da = *da_p;
#pragma unroll
  for (int ni = 0; ni < 4; ++ni) {
    const int col = n0 + wn * 128 + ni * 32 + li32;
    const float dbv = db[col];
#pragma unroll
    for (int mi = 0; mi < 4; ++mi) {
      const int rowb = m0 + wm * 128 + mi * 32 + kg2 * 4;
#pragma unroll
      for (int rq = 0; rq < 4; ++rq) {
#pragma unroll
        for (int rr = 0; rr < 4; ++rr)
          out[(size_t)(rowb + rq * 8 + rr) * H_DIM + col] =
              (float)acc[mi][ni][rq * 4 + rr] * da + dbv;
      }
    }
  }
}

extern "C" void kernel_launch(void* const* d_in, const int* in_sizes, int n_in,
                              void* d_out, int out_size, void* d_ws, size_t ws_size,
                              hipStream_t stream) {
  const int*   hs = (const int*)d_in[0];
  const int*   gw = (const int*)d_in[1];
  const float* ga = (const float*)d_in[2];
  const float* gb = (const float*)d_in[3];
  const int*   uw = (const int*)d_in[4];
  const float* ua = (const float*)d_in[5];
  const float* ub = (const float*)d_in[6];
  const int*   dw = (const int*)d_in[7];
  const float* da = (const float*)d_in[8];
  const float* db = (const float*)d_in[9];

  char* ws   = (char*)d_ws;
  char* hidS = ws;                                  // [256][128][64][16] shuffled
  char* gS   = hidS + (size_t)T_DIM * H_DIM;        // [344][128][64][16]
  char* uS   = gS   + (size_t)I_DIM * H_DIM;
  char* dS   = uS   + (size_t)I_DIM * H_DIM;        // [128][344][64][16]
  char* qS   = dS   + (size_t)H_DIM * I_DIM;        // [256][344][64][16]

  pack_shuf<<<2048, 256, 0, stream>>>(hs, hidS, H_DIM / 32, (long)T_DIM * H_DIM / 16);
  pack_shuf<<<2048, 256, 0, stream>>>(gw, gS,   H_DIM / 32, (long)I_DIM * H_DIM / 16);
  pack_shuf<<<2048, 256, 0, stream>>>(uw, uS,   H_DIM / 32, (long)I_DIM * H_DIM / 16);
  pack_shuf<<<2048, 256, 0, stream>>>(dw, dS,   I_DIM / 32, (long)H_DIM * I_DIM / 16);

  gemm_gateup<<<2752, 256, 0, stream>>>(hidS, gS, uS, ga, gb, ua, ub, qS);
  gemm_down<<<512, 256, 0, stream>>>(qS, dS, da, db, (float*)d_out);
}

// Round 11
// 1178.325 us; speedup vs baseline: 1.7325x; 1.7129x over previous
//
#include <hip/hip_runtime.h>
#include <math.h>

#define T_DIM 8192
#define H_DIM 4096
#define I_DIM 11008

typedef int v4i  __attribute__((ext_vector_type(4)));
typedef int v16i __attribute__((ext_vector_type(16)));

#define MFMA8 __builtin_amdgcn_mfma_i32_32x32x32_i8

#define AS1(p) ((const __attribute__((address_space(1))) void*)(p))
#define AS3(p) ((__attribute__((address_space(3))) void*)(p))

// counted vmcnt wait (never 0 in steady loop)
#define WAITV(N) asm volatile("s_waitcnt vmcnt(" #N ")" ::: "memory")
#define BAR() __builtin_amdgcn_s_barrier()
// LDS wait + scheduler fence (rule #18: closes ds_read -> MFMA)
#define LGKM0 do { asm volatile("s_waitcnt lgkmcnt(0)" ::: "memory"); \
                   __builtin_amdgcn_sched_barrier(0); } while (0)

__device__ __forceinline__ v4i DSR(const char* p) {
  v4i r;
  unsigned a = (unsigned)(size_t)(const __attribute__((address_space(3))) char*)p;
  asm volatile("ds_read_b128 %0, %1" : "=v"(r) : "v"(a));
  return r;
}

// One STG = one whole 1KB fragment per wave (wave-uniform LDS base + lane*16).
#define STG(ldst, gsrc) \
  __builtin_amdgcn_global_load_lds(AS1(gsrc), AS3(ldst), 16, 0, 0)

// ---------------- pack + shuffle into MFMA-fragment order (r3/r4-verified) ----
__global__ void pack_shuf(const int* __restrict__ src, char* __restrict__ dst,
                          int nk32, long nchunk) {
  long c = (long)blockIdx.x * blockDim.x + threadIdx.x;
  long stride = (long)gridDim.x * blockDim.x;
  for (; c < nchunk; c += stride) {
    int lane = (int)(c & 63);
    long rk = c >> 6;
    long r32 = rk / nk32;
    int k32 = (int)(rk - r32 * nk32);
    const int4* s = (const int4*)(src + (r32 * 32 + (lane & 31)) * (long)(nk32 * 32)
                                      + (long)k32 * 32 + ((lane >> 5) << 4));
    int4 a = s[0], b = s[1], cc = s[2], d = s[3];
    int w0 = (a.x & 255) | ((a.y & 255) << 8) | ((a.z & 255) << 16) | (a.w << 24);
    int w1 = (b.x & 255) | ((b.y & 255) << 8) | ((b.z & 255) << 16) | (b.w << 24);
    int w2 = (cc.x & 255) | ((cc.y & 255) << 8) | ((cc.z & 255) << 16) | (cc.w << 24);
    int w3 = (d.x & 255) | ((d.y & 255) << 8) | ((d.z & 255) << 16) | (d.w << 24);
    ((int4*)dst)[c] = make_int4(w0, w1, w2, w3);
  }
}

// ---------------- gate+up fused GEMM: ANTI-PHASE waves ----------------
// 256x128 tile, 8 waves (2M x 4N), wave = 128x32 x {gate,up}, BK=64.
// 3x32KB bufs, distance-2 DMA, counted vmcnt(4). Waves 0-3 compute k-steps
// s0->s1; waves 4-7 compute s1->s0 (SIMD partners w,w+4 in anti-phase:
// one issues MFMA while the other issues ds_reads -> port || matrix pipe).
__global__ __launch_bounds__(512, 2) void gemm_gateup(
    const char* __restrict__ A, const char* __restrict__ Bg, const char* __restrict__ Bu,
    const float* __restrict__ ga_p, const float* __restrict__ gb,
    const float* __restrict__ ua_p, const float* __restrict__ ub,
    char* __restrict__ Q)
{
  __shared__ char lds[3][32768];
  const int tid = threadIdx.x;
  const int l = tid & 63;
  const int w = tid >> 6;          // 8 waves
  const int wm = w >> 2, wn = w & 3;
  const int li32 = l & 31, kg2 = l >> 5;

  // XCD-chunked bijection (nwg=2752, %8==0) + 4x2 supertile.
  const int q8 = 2752 / 8;
  int bid = blockIdx.x;
  int wgid = (bid & 7) * q8 + (bid >> 3);
  int st = wgid >> 3, r = wgid & 7;
  int sm = st / 43, sn = st - sm * 43;
  const int m0 = (sm * 4 + (r & 3)) * 256;
  const int n0 = (sn * 2 + (r >> 2)) * 128;

  const int NK = H_DIM / 32;   // 128
  const int NT = H_DIM / 64;   // 64 K-tiles

  v16i accg[4], accu[4];
#pragma unroll
  for (int i = 0; i < 4; ++i)
#pragma unroll
    for (int j = 0; j < 16; ++j) { accg[i][j] = 0; accu[i][j] = 0; }

  const int lo = l * 16;
  // Staging (r7-verified): wave w stages A frag (r32=w, ks=0/1) + G,U frag
  // (n32=w>>1, ks=w&1) = 4 DMAs/tile.
  const char* pA0 = A  + ((size_t)((m0 >> 5) + w) * NK + 0) * 1024 + lo;
  const char* pA1 = A  + ((size_t)((m0 >> 5) + w) * NK + 1) * 1024 + lo;
  const char* pG  = Bg + ((size_t)((n0 >> 5) + (w >> 1)) * NK + (w & 1)) * 1024 + lo;
  const char* pU  = Bu + ((size_t)((n0 >> 5) + (w >> 1)) * NK + (w & 1)) * 1024 + lo;
  const int dA0 = w * 2048 + lo;
  const int dA1 = dA0 + 1024;
  const int dG  = 16384 + w * 1024 + lo;
  const int dU  = dG + 8192;

#define STAGE_GU(SB, tt)                                                  \
  do {                                                                    \
    size_t so = (size_t)(tt) * 2048;                                      \
    STG((SB) + dA0, pA0 + so);                                            \
    STG((SB) + dA1, pA1 + so);                                            \
    STG((SB) + dG,  pG  + so);                                            \
    STG((SB) + dU,  pU  + so);                                            \
  } while (0)

  // Anti-phase step order: waves 0-3 do (s0,s1); waves 4-7 do (s1,s0).
  const int sF = (w < 4) ? 0 : 1;
  const int sS = 1 - sF;

  // First/second-step read offsets (precomputed, no per-iter math).
  const int fA0 = (wm * 4 + 0) * 2048 + lo + sF * 1024;
  const int fA1 = (wm * 4 + 1) * 2048 + lo + sF * 1024;
  const int fA2 = (wm * 4 + 2) * 2048 + lo + sF * 1024;
  const int fA3 = (wm * 4 + 3) * 2048 + lo + sF * 1024;
  const int fG  = 16384 + wn * 2048 + lo + sF * 1024;
  const int fU  = 24576 + wn * 2048 + lo + sF * 1024;
  const int gA0 = (wm * 4 + 0) * 2048 + lo + sS * 1024;
  const int gA1 = (wm * 4 + 1) * 2048 + lo + sS * 1024;
  const int gA2 = (wm * 4 + 2) * 2048 + lo + sS * 1024;
  const int gA3 = (wm * 4 + 3) * 2048 + lo + sS * 1024;
  const int gG  = 16384 + wn * 2048 + lo + sS * 1024;
  const int gU  = 24576 + wn * 2048 + lo + sS * 1024;

  v4i E0, E1, E2, E3, Eg, Eu;
  v4i O0, O1, O2, O3, Og, Ou;

#define MM_GU(S)                                                          \
  do {                                                                    \
    __builtin_amdgcn_s_setprio(1);                                        \
    accg[0] = MFMA8(S##0, S##g, accg[0], 0, 0, 0);                        \
    accu[0] = MFMA8(S##0, S##u, accu[0], 0, 0, 0);                        \
    accg[1] = MFMA8(S##1, S##g, accg[1], 0, 0, 0);                        \
    accu[1] = MFMA8(S##1, S##u, accu[1], 0, 0, 0);                        \
    accg[2] = MFMA8(S##2, S##g, accg[2], 0, 0, 0);                        \
    accu[2] = MFMA8(S##2, S##u, accu[2], 0, 0, 0);                        \
    accg[3] = MFMA8(S##3, S##g, accg[3], 0, 0, 0);                        \
    accu[3] = MFMA8(S##3, S##u, accu[3], 0, 0, 0);                        \
    __builtin_amdgcn_s_setprio(0);                                        \
  } while (0)

  char* b0 = lds[0];
  char* b1 = lds[1];
  char* b2 = lds[2];

  {  // Prologue: stage tiles 0,1; certify tile 0 via counted vmcnt(4).
    STAGE_GU(b0, 0);
    STAGE_GU(b1, 1);
    WAITV(4);
    BAR();
  }

  for (int t = 0; t < NT; ++t) {
    const int ts = (t + 2 < NT) ? (t + 2) : (NT - 1);  // tail-clamped dup
    // First step (group-dependent): read 6 frags; stage t+2; MFMA.
    E0 = DSR(b0 + fA0); E1 = DSR(b0 + fA1);
    E2 = DSR(b0 + fA2); E3 = DSR(b0 + fA3);
    Eg = DSR(b0 + fG);  Eu = DSR(b0 + fU);
    STAGE_GU(b2, ts);
    LGKM0;
    MM_GU(E);
    // Second step: read other 6 frags; MFMA. (SIMD partner is in its MFMA
    // cluster while we read, and vice versa.)
    O0 = DSR(b0 + gA0); O1 = DSR(b0 + gA1);
    O2 = DSR(b0 + gA2); O3 = DSR(b0 + gA3);
    Og = DSR(b0 + gG);  Ou = DSR(b0 + gU);
    LGKM0;
    MM_GU(O);
    // Tile boundary: counted wait retires t+1's 4 DMAs (issued a full tile
    // ago); barrier certifies b1 for all AND closes all reads of b0 before
    // anyone stages into it next iteration.
    WAITV(4);
    BAR();
    char* tmp = b0; b0 = b1; b1 = b2; b2 = tmp;
  }
  WAITV(0);   // drain tail DMAs
#undef MM_GU
#undef STAGE_GU

  // Epilogue (r4/r7-verified): dequant -> SiLU(g)*u -> rint -> clamp -> int8,
  // written in DOWN's shuffled layout [r32][k32=col/32][lane][16B].
  const float ga = *ga_p, ua = *ua_p;
  const int col = n0 + wn * 32 + li32;
  const float gbv = gb[col], ubv = ub[col];
  const int k32q = (n0 >> 5) + wn;
  const int lanehi = ((li32 >> 4) & 1) << 5;
  const int bytelo = li32 & 15;
  const int NKQ = I_DIM / 32;  // 344
#pragma unroll
  for (int mi = 0; mi < 4; ++mi) {
    const int r32q = (m0 >> 5) + wm * 4 + mi;
    char* qbase = Q + ((size_t)(r32q * NKQ + k32q) << 10);
#pragma unroll
    for (int rq = 0; rq < 4; ++rq) {
#pragma unroll
      for (int rr = 0; rr < 4; ++rr) {
        const int rg = rq * 4 + rr;
        const int rowin = kg2 * 4 + rq * 8 + rr;
        float g = (float)accg[mi][rg] * ga + gbv;
        float u = (float)accu[mi][rg] * ua + ubv;
        float x1 = g / (1.0f + expf(-g));
        float x = rintf(x1 * u);
        x = fminf(fmaxf(x, -128.0f), 127.0f);
        qbase[((rowin | lanehi) << 4) + bytelo] = (char)(int)x;
      }
    }
  }
}

// ---------------- down GEMM: ANTI-PHASE waves ----------------
// 256x256 tile, 8 waves (2M x 4N), wave = 128x64, BK=64, 3x32KB bufs,
// distance-2, counted vmcnt(4). Same anti-phase step ordering.
__global__ __launch_bounds__(512, 2) void gemm_down(
    const char* __restrict__ Qm, const char* __restrict__ Bd,
    const float* __restrict__ da_p, const float* __restrict__ db,
    float* __restrict__ out)
{
  __shared__ char lds[3][32768];
  const int tid = threadIdx.x;
  const int l = tid & 63;
  const int w = tid >> 6;
  const int wm = w >> 2, wn = w & 3;
  const int li32 = l & 31, kg2 = l >> 5;

  const int q8 = 512 / 8;
  int bid = blockIdx.x;
  int wgid = (bid & 7) * q8 + (bid >> 3);
  int st = wgid >> 3, r = wgid & 7;
  int sm = st >> 3, sn = st & 7;
  const int m0 = (sm * 4 + (r & 3)) * 256;
  const int n0 = (sn * 2 + (r >> 2)) * 256;

  const int NK = I_DIM / 32;   // 344
  const int NT = I_DIM / 64;   // 172 K-tiles

  v16i acc[4][2];
#pragma unroll
  for (int i = 0; i < 4; ++i)
#pragma unroll
    for (int n = 0; n < 2; ++n)
#pragma unroll
      for (int j = 0; j < 16; ++j) acc[i][n][j] = 0;

  const int lo = l * 16;
  const char* pA0 = Qm + ((size_t)((m0 >> 5) + w) * NK + 0) * 1024 + lo;
  const char* pA1 = Qm + ((size_t)((m0 >> 5) + w) * NK + 1) * 1024 + lo;
  const char* pB0 = Bd + ((size_t)((n0 >> 5) + w) * NK + 0) * 1024 + lo;
  const char* pB1 = Bd + ((size_t)((n0 >> 5) + w) * NK + 1) * 1024 + lo;
  const int dA0 = w * 2048 + lo;
  const int dA1 = dA0 + 1024;
  const int dB0 = 16384 + w * 2048 + lo;
  const int dB1 = dB0 + 1024;

#define STAGE_DN(SB, tt)                                                  \
  do {                                                                    \
    size_t so = (size_t)(tt) * 2048;                                      \
    STG((SB) + dA0, pA0 + so);                                            \
    STG((SB) + dA1, pA1 + so);                                            \
    STG((SB) + dB0, pB0 + so);                                            \
    STG((SB) + dB1, pB1 + so);                                            \
  } while (0)

  const int sF = (w < 4) ? 0 : 1;
  const int sS = 1 - sF;

  const int fA0 = (wm * 4 + 0) * 2048 + lo + sF * 1024;
  const int fA1 = (wm * 4 + 1) * 2048 + lo + sF * 1024;
  const int fA2 = (wm * 4 + 2) * 2048 + lo + sF * 1024;
  const int fA3 = (wm * 4 + 3) * 2048 + lo + sF * 1024;
  const int fB0 = 16384 + (wn * 2 + 0) * 2048 + lo + sF * 1024;
  const int fB1 = 16384 + (wn * 2 + 1) * 2048 + lo + sF * 1024;
  const int gA0 = (wm * 4 + 0) * 2048 + lo + sS * 1024;
  const int gA1 = (wm * 4 + 1) * 2048 + lo + sS * 1024;
  const int gA2 = (wm * 4 + 2) * 2048 + lo + sS * 1024;
  const int gA3 = (wm * 4 + 3) * 2048 + lo + sS * 1024;
  const int gB0 = 16384 + (wn * 2 + 0) * 2048 + lo + sS * 1024;
  const int gB1 = 16384 + (wn * 2 + 1) * 2048 + lo + sS * 1024;

  v4i E0, E1, E2, E3, Eb0, Eb1;
  v4i O0, O1, O2, O3, Ob0, Ob1;

#define MM_DN(S)                                                          \
  do {                                                                    \
    __builtin_amdgcn_s_setprio(1);                                        \
    acc[0][0] = MFMA8(S##0, S##b0, acc[0][0], 0, 0, 0);                   \
    acc[0][1] = MFMA8(S##0, S##b1, acc[0][1], 0, 0, 0);                   \
    acc[1][0] = MFMA8(S##1, S##b0, acc[1][0], 0, 0, 0);                   \
    acc[1][1] = MFMA8(S##1, S##b1, acc[1][1], 0, 0, 0);                   \
    acc[2][0] = MFMA8(S##2, S##b0, acc[2][0], 0, 0, 0);                   \
    acc[2][1] = MFMA8(S##2, S##b1, acc[2][1], 0, 0, 0);                   \
    acc[3][0] = MFMA8(S##3, S##b0, acc[3][0], 0, 0, 0);                   \
    acc[3][1] = MFMA8(S##3, S##b1, acc[3][1], 0, 0, 0);                   \
    __builtin_amdgcn_s_setprio(0);                                        \
  } while (0)

  char* b0 = lds[0];
  char* b1 = lds[1];
  char* b2 = lds[2];

  {
    STAGE_DN(b0, 0);
    STAGE_DN(b1, 1);
    WAITV(4);
    BAR();
  }

  for (int t = 0; t < NT; ++t) {
    const int ts = (t + 2 < NT) ? (t + 2) : (NT - 1);
    E0 = DSR(b0 + fA0);  E1 = DSR(b0 + fA1);
    E2 = DSR(b0 + fA2);  E3 = DSR(b0 + fA3);
    Eb0 = DSR(b0 + fB0); Eb1 = DSR(b0 + fB1);
    STAGE_DN(b2, ts);
    LGKM0;
    MM_DN(E);

    O0 = DSR(b0 + gA0);  O1 = DSR(b0 + gA1);
    O2 = DSR(b0 + gA2);  O3 = DSR(b0 + gA3);
    Ob0 = DSR(b0 + gB0); Ob1 = DSR(b0 + gB1);
    LGKM0;
    MM_DN(O);

    WAITV(4);
    BAR();
    char* tmp = b0; b0 = b1; b1 = b2; b2 = tmp;
  }
  WAITV(0);
#undef MM_DN
#undef STAGE_DN

  const float da = *da_p;
#pragma unroll
  for (int ni = 0; ni < 2; ++ni) {
    const int col = n0 + wn * 64 + ni * 32 + li32;
    const float dbv = db[col];
#pragma unroll
    for (int mi = 0; mi < 4; ++mi) {
      const int rowb = m0 + wm * 128 + mi * 32 + kg2 * 4;
#pragma unroll
      for (int rq = 0; rq < 4; ++rq) {
#pragma unroll
        for (int rr = 0; rr < 4; ++rr)
          out[(size_t)(rowb + rq * 8 + rr) * H_DIM + col] =
              (float)acc[mi][ni][rq * 4 + rr] * da + dbv;
      }
    }
  }
}

extern "C" void kernel_launch(void* const* d_in, const int* in_sizes, int n_in,
                              void* d_out, int out_size, void* d_ws, size_t ws_size,
                              hipStream_t stream) {
  const int*   hs = (const int*)d_in[0];
  const int*   gw = (const int*)d_in[1];
  const float* ga = (const float*)d_in[2];
  const float* gb = (const float*)d_in[3];
  const int*   uw = (const int*)d_in[4];
  const float* ua = (const float*)d_in[5];
  const float* ub = (const float*)d_in[6];
  const int*   dw = (const int*)d_in[7];
  const float* da = (const float*)d_in[8];
  const float* db = (const float*)d_in[9];

  char* ws   = (char*)d_ws;
  char* hidS = ws;                                  // [256][128][64][16] shuffled
  char* gS   = hidS + (size_t)T_DIM * H_DIM;        // [344][128][64][16]
  char* uS   = gS   + (size_t)I_DIM * H_DIM;
  char* dS   = uS   + (size_t)I_DIM * H_DIM;        // [128][344][64][16]
  char* qS   = dS   + (size_t)H_DIM * I_DIM;        // [256][344][64][16]

  pack_shuf<<<2048, 256, 0, stream>>>(hs, hidS, H_DIM / 32, (long)T_DIM * H_DIM / 16);
  pack_shuf<<<2048, 256, 0, stream>>>(gw, gS,   H_DIM / 32, (long)I_DIM * H_DIM / 16);
  pack_shuf<<<2048, 256, 0, stream>>>(uw, uS,   H_DIM / 32, (long)I_DIM * H_DIM / 16);
  pack_shuf<<<2048, 256, 0, stream>>>(dw, dS,   I_DIM / 32, (long)H_DIM * I_DIM / 16);

  gemm_gateup<<<2752, 512, 0, stream>>>(hidS, gS, uS, ga, gb, ua, ub, qS);
  gemm_down<<<512, 512, 0, stream>>>(qS, dS, da, db, (float*)d_out);
}

// Round 12
// 1100.085 us; speedup vs baseline: 1.8558x; 1.0711x over previous
//
#include <hip/hip_runtime.h>
#include <math.h>

#define T_DIM 8192
#define H_DIM 4096
#define I_DIM 11008

typedef int v4i  __attribute__((ext_vector_type(4)));
typedef int v16i __attribute__((ext_vector_type(16)));

#define MFMA8 __builtin_amdgcn_mfma_i32_32x32x32_i8

#define AS1(p) ((const __attribute__((address_space(1))) void*)(p))
#define AS3(p) ((__attribute__((address_space(3))) void*)(p))

// counted vmcnt wait (never 0 in steady loop)
#define WAITV(N) asm volatile("s_waitcnt vmcnt(" #N ")" ::: "memory")
#define BAR() __builtin_amdgcn_s_barrier()
// counted LDS wait + scheduler fence (rule #18: closes ds_read -> MFMA)
#define LGKM(N) do { asm volatile("s_waitcnt lgkmcnt(" #N ")" ::: "memory"); \
                     __builtin_amdgcn_sched_barrier(0); } while (0)

// ds_read_b128 with compile-time immediate offset: ZERO address VALU per read.
#define DSRO(dst, base, off) \
  asm volatile("ds_read_b128 %0, %1 offset:%c2" : "=v"(dst) : "v"(base), "i"(off))

__device__ __forceinline__ unsigned ldsa(const char* p) {
  return (unsigned)(size_t)(const __attribute__((address_space(3))) char*)p;
}

// One STG = one whole 1KB fragment per wave (wave-uniform LDS base + lane*16).
#define STG(ldst, gsrc) \
  __builtin_amdgcn_global_load_lds(AS1(gsrc), AS3(ldst), 16, 0, 0)

// ---------------- pack + shuffle into MFMA-fragment order (r3/r4-verified) ----
__global__ void pack_shuf(const int* __restrict__ src, char* __restrict__ dst,
                          int nk32, long nchunk) {
  long c = (long)blockIdx.x * blockDim.x + threadIdx.x;
  long stride = (long)gridDim.x * blockDim.x;
  for (; c < nchunk; c += stride) {
    int lane = (int)(c & 63);
    long rk = c >> 6;
    long r32 = rk / nk32;
    int k32 = (int)(rk - r32 * nk32);
    const int4* s = (const int4*)(src + (r32 * 32 + (lane & 31)) * (long)(nk32 * 32)
                                      + (long)k32 * 32 + ((lane >> 5) << 4));
    int4 a = s[0], b = s[1], cc = s[2], d = s[3];
    int w0 = (a.x & 255) | ((a.y & 255) << 8) | ((a.z & 255) << 16) | (a.w << 24);
    int w1 = (b.x & 255) | ((b.y & 255) << 8) | ((b.z & 255) << 16) | (b.w << 24);
    int w2 = (cc.x & 255) | ((cc.y & 255) << 8) | ((cc.z & 255) << 16) | (cc.w << 24);
    int w3 = (d.x & 255) | ((d.y & 255) << 8) | ((d.z & 255) << 16) | (d.w << 24);
    ((int4*)dst)[c] = make_int4(w0, w1, w2, w3);
  }
}

// ---------------- gate+up fused GEMM (r7 schedule + imm-offset addressing) ----
// 256x128 tile, 8 waves (2M x 4N), wave = 128x32 x {gate,up}, BK=64.
// 4x32KB bufs, unroll-4 (buffer index compile-time), distance-2 DMA,
// counted vmcnt(4), one-phase-ahead ds_reads with LGKM(6).
__global__ __launch_bounds__(512, 1) void gemm_gateup(
    const char* __restrict__ A, const char* __restrict__ Bg, const char* __restrict__ Bu,
    const float* __restrict__ ga_p, const float* __restrict__ gb,
    const float* __restrict__ ua_p, const float* __restrict__ ub,
    char* __restrict__ Q)
{
  __shared__ char lds[131072];   // 4 x 32KB buffers
  const int tid = threadIdx.x;
  const int l = tid & 63;
  const int w = tid >> 6;          // 8 waves
  const int wm = w >> 2, wn = w & 3;
  const int li32 = l & 31, kg2 = l >> 5;

  // XCD-chunked bijection (nwg=2752, %8==0) + 4x2 supertile.
  const int q8 = 2752 / 8;
  int bid = blockIdx.x;
  int wgid = (bid & 7) * q8 + (bid >> 3);
  int st = wgid >> 3, r = wgid & 7;
  int sm = st / 43, sn = st - sm * 43;
  const int m0 = (sm * 4 + (r & 3)) * 256;
  const int n0 = (sn * 2 + (r >> 2)) * 128;

  const int NK = H_DIM / 32;   // 128
  const int NT = H_DIM / 64;   // 64 K-tiles (divisible by 4)

  v16i accg[4], accu[4];
#pragma unroll
  for (int i = 0; i < 4; ++i)
#pragma unroll
    for (int j = 0; j < 16; ++j) { accg[i][j] = 0; accu[i][j] = 0; }

  const int lo = l * 16;
  // Staging (r7-verified): wave w stages A frag (r32=w, ks=0/1) + G,U frag
  // (n32=w>>1, ks=w&1) = 4 DMAs/tile.
  const char* pA0 = A  + ((size_t)((m0 >> 5) + w) * NK + 0) * 1024 + lo;
  const char* pA1 = A  + ((size_t)((m0 >> 5) + w) * NK + 1) * 1024 + lo;
  const char* pG  = Bg + ((size_t)((n0 >> 5) + (w >> 1)) * NK + (w & 1)) * 1024 + lo;
  const char* pU  = Bu + ((size_t)((n0 >> 5) + (w >> 1)) * NK + (w & 1)) * 1024 + lo;
  const int dA0 = w * 2048 + lo;
  const int dA1 = dA0 + 1024;
  const int dG  = 16384 + w * 1024 + lo;
  const int dU  = dG + 8192;

  // Stage into buffer with compile-time offset BO.
#define STAGE_GU(BO, tt)                                                  \
  do {                                                                    \
    size_t so = (size_t)(tt) * 2048;                                      \
    STG(lds + (BO) + dA0, pA0 + so);                                      \
    STG(lds + (BO) + dA1, pA1 + so);                                      \
    STG(lds + (BO) + dG,  pG  + so);                                      \
    STG(lds + (BO) + dU,  pU  + so);                                      \
  } while (0)

  // Per-lane fragment base addresses (lo half: bufs 0-1; hi half: bufs 2-3).
  const unsigned aA0L = ldsa(lds + (wm * 4 + 0) * 2048 + lo);
  const unsigned aA1L = ldsa(lds + (wm * 4 + 1) * 2048 + lo);
  const unsigned aA2L = ldsa(lds + (wm * 4 + 2) * 2048 + lo);
  const unsigned aA3L = ldsa(lds + (wm * 4 + 3) * 2048 + lo);
  const unsigned aGL  = ldsa(lds + 16384 + wn * 2048 + lo);
  const unsigned aUL  = ldsa(lds + 24576 + wn * 2048 + lo);
  const unsigned aA0H = aA0L + 65536, aA1H = aA1L + 65536;
  const unsigned aA2H = aA2L + 65536, aA3H = aA3L + 65536;
  const unsigned aGH  = aGL  + 65536, aUH  = aUL  + 65536;

  v4i E0, E1, E2, E3, Eg, Eu;
  v4i O0, O1, O2, O3, Og, Ou;

  // RD with half-select H in {L,H} and immediate IMM = bufrel*32768 + s*1024.
#define RD_GU(S, H, IMM)                                                  \
  do {                                                                    \
    DSRO(S##0, aA0##H, IMM); DSRO(S##1, aA1##H, IMM);                     \
    DSRO(S##2, aA2##H, IMM); DSRO(S##3, aA3##H, IMM);                     \
    DSRO(S##g, aG##H,  IMM); DSRO(S##u, aU##H,  IMM);                     \
  } while (0)

#define MM_GU(S)                                                          \
  do {                                                                    \
    __builtin_amdgcn_s_setprio(1);                                        \
    accg[0] = MFMA8(S##0, S##g, accg[0], 0, 0, 0);                        \
    accu[0] = MFMA8(S##0, S##u, accu[0], 0, 0, 0);                        \
    accg[1] = MFMA8(S##1, S##g, accg[1], 0, 0, 0);                        \
    accu[1] = MFMA8(S##1, S##u, accu[1], 0, 0, 0);                        \
    accg[2] = MFMA8(S##2, S##g, accg[2], 0, 0, 0);                        \
    accu[2] = MFMA8(S##2, S##u, accu[2], 0, 0, 0);                        \
    accg[3] = MFMA8(S##3, S##g, accg[3], 0, 0, 0);                        \
    accu[3] = MFMA8(S##3, S##u, accu[3], 0, 0, 0);                        \
    __builtin_amdgcn_s_setprio(0);                                        \
  } while (0)

  {  // Prologue: stage tiles 0,1 into bufs 0,1; certify tile 0; read E(s0).
    STAGE_GU(0, 0);
    STAGE_GU(32768, 1);
    WAITV(4);
    BAR();
    RD_GU(E, L, 0);
  }

  // One tile with compile-time buffer indices: CURH/CURI = this tile's buf,
  // NXTH/NXTI = next tile's buf, SBO = staging buf offset ((u+2)&3)*32768.
#define TILE_GU(t, CURH, CURI, NXTH, NXTI, SBO)                           \
  do {                                                                    \
    const int ts = ((t) + 2 < NT) ? ((t) + 2) : (NT - 1);                 \
    RD_GU(O, CURH, (CURI) + 1024);      /* s1, one phase ahead */         \
    STAGE_GU(SBO, ts);                                                    \
    LGKM(6);                            /* retires E's reads */           \
    MM_GU(E);                                                             \
    WAITV(4);                           /* certify next tile's buffer */  \
    BAR();                                                                \
    if ((t) + 1 < NT) {                                                   \
      RD_GU(E, NXTH, NXTI);             /* next tile s0 */                \
      LGKM(6);                          /* retires O's reads */           \
    } else {                                                              \
      LGKM(0);                                                            \
    }                                                                     \
    MM_GU(O);                                                             \
  } while (0)

  for (int g = 0; g < NT / 4; ++g) {
    const int t = g * 4;
    TILE_GU(t + 0, L, 0,     L, 32768, 65536);
    TILE_GU(t + 1, L, 32768, H, 0,     98304);
    TILE_GU(t + 2, H, 0,     H, 32768, 0);
    TILE_GU(t + 3, H, 32768, L, 0,     32768);
  }
  WAITV(0);   // drain tail DMAs
#undef TILE_GU
#undef RD_GU
#undef MM_GU
#undef STAGE_GU

  // Epilogue (r4/r7-verified): dequant -> SiLU(g)*u -> rint -> clamp -> int8,
  // written in DOWN's shuffled layout [r32][k32=col/32][lane][16B].
  const float ga = *ga_p, ua = *ua_p;
  const int col = n0 + wn * 32 + li32;
  const float gbv = gb[col], ubv = ub[col];
  const int k32q = (n0 >> 5) + wn;
  const int lanehi = ((li32 >> 4) & 1) << 5;
  const int bytelo = li32 & 15;
  const int NKQ = I_DIM / 32;  // 344
#pragma unroll
  for (int mi = 0; mi < 4; ++mi) {
    const int r32q = (m0 >> 5) + wm * 4 + mi;
    char* qbase = Q + ((size_t)(r32q * NKQ + k32q) << 10);
#pragma unroll
    for (int rq = 0; rq < 4; ++rq) {
#pragma unroll
      for (int rr = 0; rr < 4; ++rr) {
        const int rg = rq * 4 + rr;
        const int rowin = kg2 * 4 + rq * 8 + rr;
        float g = (float)accg[mi][rg] * ga + gbv;
        float u = (float)accu[mi][rg] * ua + ubv;
        float x1 = g / (1.0f + expf(-g));
        float x = rintf(x1 * u);
        x = fminf(fmaxf(x, -128.0f), 127.0f);
        qbase[((rowin | lanehi) << 4) + bytelo] = (char)(int)x;
      }
    }
  }
}

// ---------------- down GEMM (r7 schedule + imm-offset addressing) ----------------
// 256x256 tile, 8 waves (2M x 4N), wave = 128x64, BK=64, 4x32KB bufs,
// unroll-4 (NT=172 divisible by 4), distance-2, counted vmcnt(4).
__global__ __launch_bounds__(512, 1) void gemm_down(
    const char* __restrict__ Qm, const char* __restrict__ Bd,
    const float* __restrict__ da_p, const float* __restrict__ db,
    float* __restrict__ out)
{
  __shared__ char lds[131072];
  const int tid = threadIdx.x;
  const int l = tid & 63;
  const int w = tid >> 6;
  const int wm = w >> 2, wn = w & 3;
  const int li32 = l & 31, kg2 = l >> 5;

  const int q8 = 512 / 8;
  int bid = blockIdx.x;
  int wgid = (bid & 7) * q8 + (bid >> 3);
  int st = wgid >> 3, r = wgid & 7;
  int sm = st >> 3, sn = st & 7;
  const int m0 = (sm * 4 + (r & 3)) * 256;
  const int n0 = (sn * 2 + (r >> 2)) * 256;

  const int NK = I_DIM / 32;   // 344
  const int NT = I_DIM / 64;   // 172 K-tiles (divisible by 4)

  v16i acc[4][2];
#pragma unroll
  for (int i = 0; i < 4; ++i)
#pragma unroll
    for (int n = 0; n < 2; ++n)
#pragma unroll
      for (int j = 0; j < 16; ++j) acc[i][n][j] = 0;

  const int lo = l * 16;
  const char* pA0 = Qm + ((size_t)((m0 >> 5) + w) * NK + 0) * 1024 + lo;
  const char* pA1 = Qm + ((size_t)((m0 >> 5) + w) * NK + 1) * 1024 + lo;
  const char* pB0 = Bd + ((size_t)((n0 >> 5) + w) * NK + 0) * 1024 + lo;
  const char* pB1 = Bd + ((size_t)((n0 >> 5) + w) * NK + 1) * 1024 + lo;
  const int dA0 = w * 2048 + lo;
  const int dA1 = dA0 + 1024;
  const int dB0 = 16384 + w * 2048 + lo;
  const int dB1 = dB0 + 1024;

#define STAGE_DN(BO, tt)                                                  \
  do {                                                                    \
    size_t so = (size_t)(tt) * 2048;                                      \
    STG(lds + (BO) + dA0, pA0 + so);                                      \
    STG(lds + (BO) + dA1, pA1 + so);                                      \
    STG(lds + (BO) + dB0, pB0 + so);                                      \
    STG(lds + (BO) + dB1, pB1 + so);                                      \
  } while (0)

  const unsigned aA0L = ldsa(lds + (wm * 4 + 0) * 2048 + lo);
  const unsigned aA1L = ldsa(lds + (wm * 4 + 1) * 2048 + lo);
  const unsigned aA2L = ldsa(lds + (wm * 4 + 2) * 2048 + lo);
  const unsigned aA3L = ldsa(lds + (wm * 4 + 3) * 2048 + lo);
  const unsigned aB0L = ldsa(lds + 16384 + (wn * 2 + 0) * 2048 + lo);
  const unsigned aB1L = ldsa(lds + 16384 + (wn * 2 + 1) * 2048 + lo);
  const unsigned aA0H = aA0L + 65536, aA1H = aA1L + 65536;
  const unsigned aA2H = aA2L + 65536, aA3H = aA3L + 65536;
  const unsigned aB0H = aB0L + 65536, aB1H = aB1L + 65536;

  v4i E0, E1, E2, E3, Eb0, Eb1;
  v4i O0, O1, O2, O3, Ob0, Ob1;

#define RD_DN(S, H, IMM)                                                  \
  do {                                                                    \
    DSRO(S##0, aA0##H, IMM);  DSRO(S##1, aA1##H, IMM);                    \
    DSRO(S##2, aA2##H, IMM);  DSRO(S##3, aA3##H, IMM);                    \
    DSRO(S##b0, aB0##H, IMM); DSRO(S##b1, aB1##H, IMM);                   \
  } while (0)

#define MM_DN(S)                                                          \
  do {                                                                    \
    __builtin_amdgcn_s_setprio(1);                                        \
    acc[0][0] = MFMA8(S##0, S##b0, acc[0][0], 0, 0, 0);                   \
    acc[0][1] = MFMA8(S##0, S##b1, acc[0][1], 0, 0, 0);                   \
    acc[1][0] = MFMA8(S##1, S##b0, acc[1][0], 0, 0, 0);                   \
    acc[1][1] = MFMA8(S##1, S##b1, acc[1][1], 0, 0, 0);                   \
    acc[2][0] = MFMA8(S##2, S##b0, acc[2][0], 0, 0, 0);                   \
    acc[2][1] = MFMA8(S##2, S##b1, acc[2][1], 0, 0, 0);                   \
    acc[3][0] = MFMA8(S##3, S##b0, acc[3][0], 0, 0, 0);                   \
    acc[3][1] = MFMA8(S##3, S##b1, acc[3][1], 0, 0, 0);                   \
    __builtin_amdgcn_s_setprio(0);                                        \
  } while (0)

  {
    STAGE_DN(0, 0);
    STAGE_DN(32768, 1);
    WAITV(4);
    BAR();
    RD_DN(E, L, 0);
  }

#define TILE_DN(t, CURH, CURI, NXTH, NXTI, SBO)                           \
  do {                                                                    \
    const int ts = ((t) + 2 < NT) ? ((t) + 2) : (NT - 1);                 \
    RD_DN(O, CURH, (CURI) + 1024);                                        \
    STAGE_DN(SBO, ts);                                                    \
    LGKM(6);                                                              \
    MM_DN(E);                                                             \
    WAITV(4);                                                             \
    BAR();                                                                \
    if ((t) + 1 < NT) {                                                   \
      RD_DN(E, NXTH, NXTI);                                               \
      LGKM(6);                                                            \
    } else {                                                              \
      LGKM(0);                                                            \
    }                                                                     \
    MM_DN(O);                                                             \
  } while (0)

  for (int g = 0; g < NT / 4; ++g) {
    const int t = g * 4;
    TILE_DN(t + 0, L, 0,     L, 32768, 65536);
    TILE_DN(t + 1, L, 32768, H, 0,     98304);
    TILE_DN(t + 2, H, 0,     H, 32768, 0);
    TILE_DN(t + 3, H, 32768, L, 0,     32768);
  }
  WAITV(0);
#undef TILE_DN
#undef RD_DN
#undef MM_DN
#undef STAGE_DN

  const float da = *da_p;
#pragma unroll
  for (int ni = 0; ni < 2; ++ni) {
    const int col = n0 + wn * 64 + ni * 32 + li32;
    const float dbv = db[col];
#pragma unroll
    for (int mi = 0; mi < 4; ++mi) {
      const int rowb = m0 + wm * 128 + mi * 32 + kg2 * 4;
#pragma unroll
      for (int rq = 0; rq < 4; ++rq) {
#pragma unroll
        for (int rr = 0; rr < 4; ++rr)
          out[(size_t)(rowb + rq * 8 + rr) * H_DIM + col] =
              (float)acc[mi][ni][rq * 4 + rr] * da + dbv;
      }
    }
  }
}

extern "C" void kernel_launch(void* const* d_in, const int* in_sizes, int n_in,
                              void* d_out, int out_size, void* d_ws, size_t ws_size,
                              hipStream_t stream) {
  const int*   hs = (const int*)d_in[0];
  const int*   gw = (const int*)d_in[1];
  const float* ga = (const float*)d_in[2];
  const float* gb = (const float*)d_in[3];
  const int*   uw = (const int*)d_in[4];
  const float* ua = (const float*)d_in[5];
  const float* ub = (const float*)d_in[6];
  const int*   dw = (const int*)d_in[7];
  const float* da = (const float*)d_in[8];
  const float* db = (const float*)d_in[9];

  char* ws   = (char*)d_ws;
  char* hidS = ws;                                  // [256][128][64][16] shuffled
  char* gS   = hidS + (size_t)T_DIM * H_DIM;        // [344][128][64][16]
  char* uS   = gS   + (size_t)I_DIM * H_DIM;
  char* dS   = uS   + (size_t)I_DIM * H_DIM;        // [128][344][64][16]
  char* qS   = dS   + (size_t)H_DIM * I_DIM;        // [256][344][64][16]

  pack_shuf<<<2048, 256, 0, stream>>>(hs, hidS, H_DIM / 32, (long)T_DIM * H_DIM / 16);
  pack_shuf<<<2048, 256, 0, stream>>>(gw, gS,   H_DIM / 32, (long)I_DIM * H_DIM / 16);
  pack_shuf<<<2048, 256, 0, stream>>>(uw, uS,   H_DIM / 32, (long)I_DIM * H_DIM / 16);
  pack_shuf<<<2048, 256, 0, stream>>>(dw, dS,   I_DIM / 32, (long)H_DIM * I_DIM / 16);

  gemm_gateup<<<2752, 512, 0, stream>>>(hidS, gS, uS, ga, gb, ua, ub, qS);
  gemm_down<<<512, 512, 0, stream>>>(qS, dS, da, db, (float*)d_out);
}